// Round 4
// baseline (431.172 us; speedup 1.0000x reference)
//
#include <hip/hip_runtime.h>
#include <hip/hip_bf16.h>
#include <stdint.h>

// B=2, N=128, D=512, LAYERS=3.
// Algebraic reduction: concat-GEMMs decompose into rank terms; only rel@Wgc (x2)
// + rel3@W_esa are big GEMMs. NEW: the whole rel chain is ONE persistent-tile
// kernel: block (b,i) keeps its 128x512 rel tile in LDS across all 3 layers,
// B-operand (weights) loaded register-direct from a fragment-packed layout
// (coalesced dwordx4 from L2). Inter-layer HBM traffic eliminated; only the
// final S (needed for the cross-i softmax) is written to HBM.

#define DEV static __device__ __forceinline__

typedef float  f32x4   __attribute__((ext_vector_type(4)));
typedef float  f32x16  __attribute__((ext_vector_type(16)));
typedef __bf16 bf16x8  __attribute__((ext_vector_type(8)));
typedef __bf16 bf16x4  __attribute__((ext_vector_type(4)));

DEV float tanh_fast(float x) {
  float e = __expf(2.0f * x);
  return 1.0f - 2.0f * __frcp_rn(e + 1.0f);
}

DEV void gl_lds16(const void* g, void* l) {
  __builtin_amdgcn_global_load_lds(
      (const __attribute__((address_space(1))) unsigned int*)g,
      (__attribute__((address_space(3))) unsigned int*)l, 16, 0, 0);
}

// ------------- prep: transposes, x0 split, dvec, fragment-pack Wgc/Wesa ---------
// Frag layout: Wf[((nt*32 + kt)*64 + lane)*8 + e] = W[k][n],
//   n = nt*32 + (lane&31), k = kt*16 + (lane>>5)*8 + e   (nt 0..15, kt 0..31)
struct WC { const float* W; __bf16* Wh; __bf16* Wl; };
struct Prep {
  WC w[6];
  const float* x0; __bf16* x0h; __bf16* x0l;
  const float* b_rel; const float* Wgrc; const float* b_gr; float* dvec;
  const float* Wesa; __bf16* Wgcf; __bf16* Wesf;
};

__global__ __launch_bounds__(256) void prep_kernel(Prep pp) {
  const int y = blockIdx.y;
  const int t = threadIdx.x;
  if (y < 6) {
    const WC wc = pp.w[y];
    __shared__ float tile[32][33];
    int tx = t & 31, ty = t >> 5;
    int bx = blockIdx.x & 15, by = blockIdx.x >> 4;
    int k0 = by * 32, n0 = bx * 32;
#pragma unroll
    for (int r = 0; r < 4; ++r) {
      int k = ty + r * 8;
      tile[k][tx] = wc.W[(size_t)(k0 + k) * 512 + n0 + tx];
    }
    __syncthreads();
#pragma unroll
    for (int r = 0; r < 4; ++r) {
      int n = ty + r * 8;
      float v = tile[tx][n];
      __bf16 h = (__bf16)v;
      wc.Wh[(size_t)(n0 + n) * 512 + k0 + tx] = h;
      wc.Wl[(size_t)(n0 + n) * 512 + k0 + tx] = (__bf16)(v - (float)h);
    }
  } else if (y == 6) {
    int i = blockIdx.x * 256 + t;
    if (i < 32768) {
      float4 v = ((const float4*)pp.x0)[i];
      float vv[4] = {v.x, v.y, v.z, v.w};
      bf16x4 h, l;
#pragma unroll
      for (int e = 0; e < 4; ++e) {
        __bf16 he = (__bf16)vv[e];
        h[e] = he;
        l[e] = (__bf16)(vv[e] - (float)he);
      }
      ((bf16x4*)pp.x0h)[i] = h;
      ((bf16x4*)pp.x0l)[i] = l;
    }
  } else if (y == 7) {
    if (blockIdx.x < 2) {
      int n = blockIdx.x * 256 + t;
      float acc = pp.b_gr[n];
#pragma unroll 8
      for (int k = 0; k < 512; ++k) acc += pp.b_rel[k] * pp.Wgrc[(size_t)k * 512 + n];
      pp.dvec[n] = acc;
    }
  } else {
    if (blockIdx.x < 128) {
      const float* W = (y == 8) ? pp.Wgrc : pp.Wesa;
      __bf16* Wf = (y == 8) ? pp.Wgcf : pp.Wesf;
      int gid = blockIdx.x * 256 + t;     // 0..32767
      int lane = gid & 63;
      int frag = gid >> 6;                // nt*32 + kt
      int kt = frag & 31, nt = frag >> 5;
      int n = nt * 32 + (lane & 31);
      int k0 = kt * 16 + (lane >> 5) * 8;
      bf16x8 o;
#pragma unroll
      for (int e = 0; e < 8; ++e) o[e] = (__bf16)W[(size_t)(k0 + e) * 512 + n];
      *(bf16x8*)&Wf[(size_t)gid * 8] = o;
    }
  }
}

// ------------- small MFMA GEMM batch: out = act(X@W + bias + add) ---------------
struct MOp {
  const __bf16* Xh; const __bf16* Xl;
  const __bf16* Wh; const __bf16* Wl;
  const float* bias;
  const float* add;
  float* outf;
  __bf16* outh; __bf16* outl;
  int act;
};
struct MBatch { MOp op[5]; };

__global__ __launch_bounds__(256, 2) void mfma_small_kernel(MBatch batch) {
  const MOp o = batch.op[blockIdx.y];
  const int m0 = ((int)blockIdx.x >> 3) * 64;
  const int n0 = ((int)blockIdx.x & 7) * 64;
  __shared__ __bf16 Ah[64 * 64], Al[64 * 64], Bh[64 * 64], Bl[64 * 64];
  const int t = threadIdx.x, lane = t & 63, wave = t >> 6;
  const int waveM = wave >> 1, waveN = wave & 1;
  const bool comp = (o.Xl != nullptr);

  f32x4 vzero = {0.f, 0.f, 0.f, 0.f};
  f32x4 acc[2][2];
#pragma unroll
  for (int a = 0; a < 2; ++a)
#pragma unroll
    for (int c = 0; c < 2; ++c) acc[a][c] = vzero;

  const int lr = lane >> 3, lc = (lane & 7) * 8;

  for (int k0 = 0; k0 < 512; k0 += 64) {
    __syncthreads();
#pragma unroll
    for (int r = 0; r < 2; ++r) {
      const int rb = r * 32 + wave * 8;
      gl_lds16(o.Xh + (size_t)(m0 + rb + lr) * 512 + k0 + lc, &Ah[rb * 64]);
      gl_lds16(o.Wh + (size_t)(n0 + rb + lr) * 512 + k0 + lc, &Bh[rb * 64]);
      if (comp) {
        gl_lds16(o.Xl + (size_t)(m0 + rb + lr) * 512 + k0 + lc, &Al[rb * 64]);
        gl_lds16(o.Wl + (size_t)(n0 + rb + lr) * 512 + k0 + lc, &Bl[rb * 64]);
      }
    }
    __syncthreads();
#pragma unroll
    for (int kk = 0; kk < 2; ++kk) {
      const int koff = kk * 32 + (lane >> 4) * 8;
      const int ml = lane & 15;
      bf16x8 ah[2], bh[2], al[2], bl[2];
#pragma unroll
      for (int tm = 0; tm < 2; ++tm)
        ah[tm] = *(const bf16x8*)&Ah[(waveM * 32 + tm * 16 + ml) * 64 + koff];
#pragma unroll
      for (int tn = 0; tn < 2; ++tn)
        bh[tn] = *(const bf16x8*)&Bh[(waveN * 32 + tn * 16 + ml) * 64 + koff];
      if (comp) {
#pragma unroll
        for (int tm = 0; tm < 2; ++tm)
          al[tm] = *(const bf16x8*)&Al[(waveM * 32 + tm * 16 + ml) * 64 + koff];
#pragma unroll
        for (int tn = 0; tn < 2; ++tn)
          bl[tn] = *(const bf16x8*)&Bl[(waveN * 32 + tn * 16 + ml) * 64 + koff];
      }
#pragma unroll
      for (int tm = 0; tm < 2; ++tm)
#pragma unroll
        for (int tn = 0; tn < 2; ++tn) {
          acc[tm][tn] = __builtin_amdgcn_mfma_f32_16x16x32_bf16(ah[tm], bh[tn], acc[tm][tn], 0, 0, 0);
          if (comp) {
            acc[tm][tn] = __builtin_amdgcn_mfma_f32_16x16x32_bf16(ah[tm], bl[tn], acc[tm][tn], 0, 0, 0);
            acc[tm][tn] = __builtin_amdgcn_mfma_f32_16x16x32_bf16(al[tm], bh[tn], acc[tm][tn], 0, 0, 0);
          }
        }
    }
  }

  const int quad = lane >> 4, cl = lane & 15;
#pragma unroll
  for (int tm = 0; tm < 2; ++tm) {
#pragma unroll
    for (int r = 0; r < 4; ++r) {
      const int row = m0 + waveM * 32 + tm * 16 + quad * 4 + r;
#pragma unroll
      for (int tn = 0; tn < 2; ++tn) {
        const int col = n0 + waveN * 32 + tn * 16 + cl;
        float v = acc[tm][tn][r];
        if (o.bias) v += o.bias[col];
        if (o.add) v += o.add[(size_t)row * 512 + col];
        if (o.act) v = tanh_fast(v);
        if (o.outf) o.outf[(size_t)row * 512 + col] = v;
        if (o.outh) {
          __bf16 h = (__bf16)v;
          o.outh[(size_t)row * 512 + col] = h;
          o.outl[(size_t)row * 512 + col] = (__bf16)(v - (float)h);
        }
      }
    }
  }
}

// ------------- fused rel chain: one block per (b,i), rel tile lives in LDS ------
// rel1 = tanh(A[i]+C[j]) -> [@Wgc +p1+q1 tanh] -> [@Wgc +p2+q2 tanh] -> @Wes+b -> S
// 512 threads (8 waves). Wave w owns cols [w*64, w*64+64) (tn=2 x 32).
// A-frags from LDS (stride 520 bf16 = 4-way-conflict pad); B-frags direct from
// fragment-packed weights (coalesced dwordx4, L2-resident).
constexpr int RS = 520;  // rel row stride (bf16), 1040 B, 16B aligned

__global__ __launch_bounds__(512, 1) void chain_kernel(
    const float* __restrict__ Abuf, const float* __restrict__ Cbuf,
    const __bf16* __restrict__ Wgcf, const __bf16* __restrict__ Wesf,
    const float* __restrict__ p1, const float* __restrict__ q1,
    const float* __restrict__ p2, const float* __restrict__ q2,
    const float* __restrict__ b_esa, float* __restrict__ S) {
  __shared__ __bf16 rel[128 * RS];
  const int t = threadIdx.x;
  const int lane = t & 63, wave = t >> 6;
  const int bm = blockIdx.x;            // b*128 + i
  const int b = bm >> 7;

  // ---- rel1 generation: 4 threads per row j ----
  {
    const int j = t >> 2, qt = (t & 3) * 128;
    const float* ap = &Abuf[(size_t)bm * 512 + qt];
    const float* cp = &Cbuf[((size_t)(b * 128 + j)) * 512 + qt];
#pragma unroll
    for (int c = 0; c < 128; c += 8) {
      float4 a0 = *(const float4*)(ap + c), a1 = *(const float4*)(ap + c + 4);
      float4 c0 = *(const float4*)(cp + c), c1 = *(const float4*)(cp + c + 4);
      float av[8] = {a0.x + c0.x, a0.y + c0.y, a0.z + c0.z, a0.w + c0.w,
                     a1.x + c1.x, a1.y + c1.y, a1.z + c1.z, a1.w + c1.w};
      bf16x8 o;
#pragma unroll
      for (int e = 0; e < 8; ++e) o[e] = (__bf16)tanh_fast(av[e]);
      *(bf16x8*)&rel[j * RS + qt + c] = o;
    }
  }
  __syncthreads();

  const int ml = lane & 31;
  const int kg = (lane >> 5) * 8;
  const int lg = lane >> 5;

  for (int l = 0; l < 3; ++l) {
    const __bf16* Wf = (l == 2) ? Wesf : Wgcf;
    f32x16 acc[4][2];
#pragma unroll
    for (int a = 0; a < 4; ++a)
#pragma unroll
      for (int c = 0; c < 2; ++c) acc[a][c] = (f32x16)0.f;

    // K loop: 32 steps of 16, 1-deep B prefetch (register-direct from L2)
    const size_t fb0 = ((size_t)((wave * 2 + 0) * 32) * 64 + lane) * 8;
    const size_t fb1 = ((size_t)((wave * 2 + 1) * 32) * 64 + lane) * 8;
    bf16x8 b0 = *(const bf16x8*)&Wf[fb0];
    bf16x8 b1 = *(const bf16x8*)&Wf[fb1];
#pragma unroll 4
    for (int kt = 0; kt < 32; ++kt) {
      const int ktn = (kt + 1) & 31;
      bf16x8 n0 = *(const bf16x8*)&Wf[fb0 + (size_t)ktn * 512];
      bf16x8 n1 = *(const bf16x8*)&Wf[fb1 + (size_t)ktn * 512];
      bf16x8 af[4];
#pragma unroll
      for (int tm = 0; tm < 4; ++tm)
        af[tm] = *(const bf16x8*)&rel[(tm * 32 + ml) * RS + kt * 16 + kg];
#pragma unroll
      for (int tm = 0; tm < 4; ++tm) {
        acc[tm][0] = __builtin_amdgcn_mfma_f32_32x32x16_bf16(af[tm], b0, acc[tm][0], 0, 0, 0);
        acc[tm][1] = __builtin_amdgcn_mfma_f32_32x32x16_bf16(af[tm], b1, acc[tm][1], 0, 0, 0);
      }
      b0 = n0; b1 = n1;
    }

    if (l < 2) {
      const float* P = l ? p2 : p1;
      const float* Q = l ? q2 : q1;
      __syncthreads();  // all A-reads of this layer done before overwrite
#pragma unroll
      for (int tn = 0; tn < 2; ++tn) {
        const int col = wave * 64 + tn * 32 + ml;
        const float pv = P[(size_t)bm * 512 + col];
#pragma unroll
        for (int tm = 0; tm < 4; ++tm) {
#pragma unroll
          for (int reg = 0; reg < 16; ++reg) {
            const int row = tm * 32 + (reg & 3) + 8 * (reg >> 2) + 4 * lg;  // j
            float v = acc[tm][tn][reg] + pv +
                      Q[((size_t)(b * 128 + row)) * 512 + col];
            rel[row * RS + col] = (__bf16)tanh_fast(v);
          }
        }
      }
      __syncthreads();
    } else {
#pragma unroll
      for (int tn = 0; tn < 2; ++tn) {
        const int col = wave * 64 + tn * 32 + ml;
        const float bv = b_esa[col];
#pragma unroll
        for (int tm = 0; tm < 4; ++tm) {
#pragma unroll
          for (int reg = 0; reg < 16; ++reg) {
            const int row = tm * 32 + (reg & 3) + 8 * (reg >> 2) + 4 * lg;  // j
            S[((size_t)bm * 128 + row) * 512 + col] = acc[tm][tn][reg] + bv;
          }
        }
      }
    }
  }
}

// ------------- softmax over axis i (no max pass: |s| bounded), then sum over j --
__global__ __launch_bounds__(256) void softmax_l_kernel(
    const float* __restrict__ S, float* __restrict__ Lb) {
  int idx = blockIdx.x * 256 + threadIdx.x;   // = (b*128 + j)*512 + d
  int d = idx & 511;
  int j = (idx >> 9) & 127;
  int b = idx >> 16;
  const float* p = S + ((size_t)b * 16384 + j) * 512 + d;  // i = 0
  float l = 0.f;
#pragma unroll 8
  for (int ii = 0; ii < 128; ++ii) l += __expf(p[(size_t)ii * 65536]);
  Lb[idx] = __frcp_rn(l);
}

__global__ __launch_bounds__(256) void softmax_out_kernel(
    const float* __restrict__ S, const float* __restrict__ Lb,
    float* __restrict__ outp) {
  int idx = blockIdx.x * 256 + threadIdx.x;   // = (b*128 + i)*512 + d
  int d = idx & 511;
  int i = (idx >> 9) & 127;
  int b = idx >> 16;
  const float* sp = S + ((size_t)(b * 128 + i)) * 65536 + d;  // j = 0
  const float* lp = Lb + (size_t)b * 65536 + d;
  float acc = 0.f;
#pragma unroll 8
  for (int jj = 0; jj < 128; ++jj) {
    float s = sp[(size_t)jj * 512];
    acc += __expf(s) * lp[(size_t)jj * 512] * s;
  }
  outp[idx] = acc;
}

// --------------------------------------------------------------------------------
extern "C" void kernel_launch(void* const* d_in, const int* in_sizes, int n_in,
                              void* d_out, int out_size, void* d_ws, size_t ws_size,
                              hipStream_t stream) {
  const float* x0    = (const float*)d_in[0];
  const float* W_rel = (const float*)d_in[1];
  const float* b_rel = (const float*)d_in[2];
  const float* W_go  = (const float*)d_in[3];
  const float* b_go  = (const float*)d_in[4];
  const float* W_gr  = (const float*)d_in[5];
  const float* b_gr  = (const float*)d_in[6];
  const float* W_esa = (const float*)d_in[7];
  const float* b_esa = (const float*)d_in[8];

  const float* Wrel_top = W_rel;
  const float* Wrel_bot = W_rel + 512 * 512;
  const float* Wgr_a = W_gr;
  const float* Wgr_b = W_gr + 512 * 512;
  const float* Wgr_c = W_gr + 2 * 512 * 512;

  char* ws = (char*)d_ws;
  size_t off = 0;
  auto alloc = [&](size_t bytes) -> void* {
    void* p = ws + off;
    off += (bytes + 255) & ~(size_t)255;
    return p;
  };
  const size_t NREL = 16777216ull;
  float*  S  = (float*)alloc(NREL * 4);        // 64 MB
  float* p0t  = (float*)alloc(131072 * 4);
  float* q0t  = (float*)alloc(131072 * 4);
  float* Abuf = (float*)alloc(131072 * 4);
  float* Cbuf = (float*)alloc(131072 * 4);
  float* p1   = (float*)alloc(131072 * 4);
  float* q1   = (float*)alloc(131072 * 4);
  float* p2   = (float*)alloc(131072 * 4);
  float* q2   = (float*)alloc(131072 * 4);
  float* dvec = (float*)alloc(512 * 4);
  float* Lb   = (float*)alloc(131072 * 4);
  __bf16* x0h = (__bf16*)alloc(131072 * 2);
  __bf16* x0l = (__bf16*)alloc(131072 * 2);
  __bf16* x1h = (__bf16*)alloc(131072 * 2);
  __bf16* x1l = (__bf16*)alloc(131072 * 2);
  __bf16* x2h = (__bf16*)alloc(131072 * 2);
  __bf16* x2l = (__bf16*)alloc(131072 * 2);
  __bf16* u0h = (__bf16*)alloc(131072 * 2);
  __bf16* u0l = (__bf16*)alloc(131072 * 2);
  __bf16* v0h = (__bf16*)alloc(131072 * 2);
  __bf16* v0l = (__bf16*)alloc(131072 * 2);
  __bf16* Wgo_h = (__bf16*)alloc(262144 * 2);
  __bf16* Wgo_l = (__bf16*)alloc(262144 * 2);
  __bf16* Wrt_h = (__bf16*)alloc(262144 * 2);
  __bf16* Wrt_l = (__bf16*)alloc(262144 * 2);
  __bf16* Wrb_h = (__bf16*)alloc(262144 * 2);
  __bf16* Wrb_l = (__bf16*)alloc(262144 * 2);
  __bf16* Wga_h = (__bf16*)alloc(262144 * 2);
  __bf16* Wga_l = (__bf16*)alloc(262144 * 2);
  __bf16* Wgb_h = (__bf16*)alloc(262144 * 2);
  __bf16* Wgb_l = (__bf16*)alloc(262144 * 2);
  __bf16* Wgc_h = (__bf16*)alloc(262144 * 2);
  __bf16* Wgc_l = (__bf16*)alloc(262144 * 2);
  __bf16* Wgcf  = (__bf16*)alloc(262144 * 2);  // fragment-packed
  __bf16* Wesf  = (__bf16*)alloc(262144 * 2);  // fragment-packed

  float* x3out  = (float*)d_out;             // output 0
  float* relout = (float*)d_out + 131072;    // output 1

  Prep pp;
  pp.w[0] = {W_go, Wgo_h, Wgo_l};
  pp.w[1] = {Wrel_top, Wrt_h, Wrt_l};
  pp.w[2] = {Wrel_bot, Wrb_h, Wrb_l};
  pp.w[3] = {Wgr_a, Wga_h, Wga_l};
  pp.w[4] = {Wgr_b, Wgb_h, Wgb_l};
  pp.w[5] = {Wgr_c, Wgc_h, Wgc_l};
  pp.x0 = x0; pp.x0h = x0h; pp.x0l = x0l;
  pp.b_rel = b_rel; pp.Wgrc = Wgr_c; pp.b_gr = b_gr; pp.dvec = dvec;
  pp.Wesa = W_esa; pp.Wgcf = Wgcf; pp.Wesf = Wesf;
  prep_kernel<<<dim3(256, 10), 256, 0, stream>>>(pp);

  MBatch m1 = {};
  m1.op[0] = {x0h, x0l, Wgo_h, Wgo_l, b_go, nullptr, nullptr, x1h, x1l, 1};
  m1.op[1] = {x0h, x0l, Wrt_h, Wrt_l, nullptr, nullptr, nullptr, u0h, u0l, 0};
  m1.op[2] = {x0h, x0l, Wrb_h, Wrb_l, nullptr, nullptr, nullptr, v0h, v0l, 0};
  m1.op[3] = {x0h, x0l, Wga_h, Wga_l, nullptr, nullptr, p0t, nullptr, nullptr, 0};
  m1.op[4] = {x0h, x0l, Wgb_h, Wgb_l, nullptr, nullptr, q0t, nullptr, nullptr, 0};
  mfma_small_kernel<<<dim3(32, 5), 256, 0, stream>>>(m1);

  MBatch m2 = {};
  m2.op[0] = {x1h, x1l, Wgo_h, Wgo_l, b_go, nullptr, nullptr, x2h, x2l, 1};
  m2.op[1] = {u0h, u0l, Wgc_h, Wgc_l, dvec, p0t, Abuf, nullptr, nullptr, 0};
  m2.op[2] = {v0h, v0l, Wgc_h, Wgc_l, nullptr, q0t, Cbuf, nullptr, nullptr, 0};
  m2.op[3] = {x1h, x1l, Wga_h, Wga_l, b_gr, nullptr, p1, nullptr, nullptr, 0};
  m2.op[4] = {x1h, x1l, Wgb_h, Wgb_l, nullptr, nullptr, q1, nullptr, nullptr, 0};
  mfma_small_kernel<<<dim3(32, 5), 256, 0, stream>>>(m2);

  MBatch m3 = {};
  m3.op[0] = {x2h, x2l, Wgo_h, Wgo_l, b_go, nullptr, x3out, nullptr, nullptr, 1};
  m3.op[1] = {x2h, x2l, Wga_h, Wga_l, b_gr, nullptr, p2, nullptr, nullptr, 0};
  m3.op[2] = {x2h, x2l, Wgb_h, Wgb_l, nullptr, nullptr, q2, nullptr, nullptr, 0};
  mfma_small_kernel<<<dim3(32, 3), 256, 0, stream>>>(m3);

  // fused rel chain (replaces rel1 + 3 big GEMMs)
  chain_kernel<<<256, 512, 0, stream>>>(Abuf, Cbuf, Wgcf, Wesf,
                                        p1, q1, p2, q2, b_esa, S);

  softmax_l_kernel<<<512, 256, 0, stream>>>(S, Lb);
  softmax_out_kernel<<<512, 256, 0, stream>>>(S, Lb, relout);
}

// Round 5
// 385.823 us; speedup vs baseline: 1.1175x; 1.1175x over previous
//
#include <hip/hip_runtime.h>
#include <hip/hip_bf16.h>
#include <stdint.h>

// B=2, N=128, D=512, LAYERS=3.
// Fused rel-chain kernel: block = (b, i, j-half) owns a 64x512 rel tile in LDS
// across all 3 layers (chain is row-independent in j, so j-tile size is free).
// 66.5 KB LDS -> 2 blocks/CU (16 waves/CU); 2-deep register prefetch of
// fragment-packed weights (L2-resident) covers load latency.

#define DEV static __device__ __forceinline__

typedef float  f32x4   __attribute__((ext_vector_type(4)));
typedef float  f32x16  __attribute__((ext_vector_type(16)));
typedef __bf16 bf16x8  __attribute__((ext_vector_type(8)));
typedef __bf16 bf16x4  __attribute__((ext_vector_type(4)));

DEV float tanh_fast(float x) {
  float e = __expf(2.0f * x);
  return 1.0f - 2.0f * __frcp_rn(e + 1.0f);
}

DEV void gl_lds16(const void* g, void* l) {
  __builtin_amdgcn_global_load_lds(
      (const __attribute__((address_space(1))) unsigned int*)g,
      (__attribute__((address_space(3))) unsigned int*)l, 16, 0, 0);
}

// ------------- prep: transposes, x0 split, dvec, fragment-pack Wgc/Wesa ---------
// Frag layout: Wf[((nt*32 + kt)*64 + lane)*8 + e] = W[k][n],
//   n = nt*32 + (lane&31), k = kt*16 + (lane>>5)*8 + e   (nt 0..15, kt 0..31)
struct WC { const float* W; __bf16* Wh; __bf16* Wl; };
struct Prep {
  WC w[6];
  const float* x0; __bf16* x0h; __bf16* x0l;
  const float* b_rel; const float* Wgrc; const float* b_gr; float* dvec;
  const float* Wesa; __bf16* Wgcf; __bf16* Wesf;
};

__global__ __launch_bounds__(256) void prep_kernel(Prep pp) {
  const int y = blockIdx.y;
  const int t = threadIdx.x;
  if (y < 6) {
    const WC wc = pp.w[y];
    __shared__ float tile[32][33];
    int tx = t & 31, ty = t >> 5;
    int bx = blockIdx.x & 15, by = blockIdx.x >> 4;
    int k0 = by * 32, n0 = bx * 32;
#pragma unroll
    for (int r = 0; r < 4; ++r) {
      int k = ty + r * 8;
      tile[k][tx] = wc.W[(size_t)(k0 + k) * 512 + n0 + tx];
    }
    __syncthreads();
#pragma unroll
    for (int r = 0; r < 4; ++r) {
      int n = ty + r * 8;
      float v = tile[tx][n];
      __bf16 h = (__bf16)v;
      wc.Wh[(size_t)(n0 + n) * 512 + k0 + tx] = h;
      wc.Wl[(size_t)(n0 + n) * 512 + k0 + tx] = (__bf16)(v - (float)h);
    }
  } else if (y == 6) {
    int i = blockIdx.x * 256 + t;
    if (i < 32768) {
      float4 v = ((const float4*)pp.x0)[i];
      float vv[4] = {v.x, v.y, v.z, v.w};
      bf16x4 h, l;
#pragma unroll
      for (int e = 0; e < 4; ++e) {
        __bf16 he = (__bf16)vv[e];
        h[e] = he;
        l[e] = (__bf16)(vv[e] - (float)he);
      }
      ((bf16x4*)pp.x0h)[i] = h;
      ((bf16x4*)pp.x0l)[i] = l;
    }
  } else if (y == 7) {
    if (blockIdx.x < 2) {
      int n = blockIdx.x * 256 + t;
      float acc = pp.b_gr[n];
#pragma unroll 8
      for (int k = 0; k < 512; ++k) acc += pp.b_rel[k] * pp.Wgrc[(size_t)k * 512 + n];
      pp.dvec[n] = acc;
    }
  } else {
    if (blockIdx.x < 128) {
      const float* W = (y == 8) ? pp.Wgrc : pp.Wesa;
      __bf16* Wf = (y == 8) ? pp.Wgcf : pp.Wesf;
      int gid = blockIdx.x * 256 + t;     // 0..32767
      int lane = gid & 63;
      int frag = gid >> 6;                // nt*32 + kt
      int kt = frag & 31, nt = frag >> 5;
      int n = nt * 32 + (lane & 31);
      int k0 = kt * 16 + (lane >> 5) * 8;
      bf16x8 o;
#pragma unroll
      for (int e = 0; e < 8; ++e) o[e] = (__bf16)W[(size_t)(k0 + e) * 512 + n];
      *(bf16x8*)&Wf[(size_t)gid * 8] = o;
    }
  }
}

// ------------- small MFMA GEMM batch: out = act(X@W + bias + add) ---------------
struct MOp {
  const __bf16* Xh; const __bf16* Xl;
  const __bf16* Wh; const __bf16* Wl;
  const float* bias;
  const float* add;
  float* outf;
  __bf16* outh; __bf16* outl;
  int act;
};
struct MBatch { MOp op[5]; };

__global__ __launch_bounds__(256, 2) void mfma_small_kernel(MBatch batch) {
  const MOp o = batch.op[blockIdx.y];
  const int m0 = ((int)blockIdx.x >> 3) * 64;
  const int n0 = ((int)blockIdx.x & 7) * 64;
  __shared__ __bf16 Ah[64 * 64], Al[64 * 64], Bh[64 * 64], Bl[64 * 64];
  const int t = threadIdx.x, lane = t & 63, wave = t >> 6;
  const int waveM = wave >> 1, waveN = wave & 1;
  const bool comp = (o.Xl != nullptr);

  f32x4 vzero = {0.f, 0.f, 0.f, 0.f};
  f32x4 acc[2][2];
#pragma unroll
  for (int a = 0; a < 2; ++a)
#pragma unroll
    for (int c = 0; c < 2; ++c) acc[a][c] = vzero;

  const int lr = lane >> 3, lc = (lane & 7) * 8;

  for (int k0 = 0; k0 < 512; k0 += 64) {
    __syncthreads();
#pragma unroll
    for (int r = 0; r < 2; ++r) {
      const int rb = r * 32 + wave * 8;
      gl_lds16(o.Xh + (size_t)(m0 + rb + lr) * 512 + k0 + lc, &Ah[rb * 64]);
      gl_lds16(o.Wh + (size_t)(n0 + rb + lr) * 512 + k0 + lc, &Bh[rb * 64]);
      if (comp) {
        gl_lds16(o.Xl + (size_t)(m0 + rb + lr) * 512 + k0 + lc, &Al[rb * 64]);
        gl_lds16(o.Wl + (size_t)(n0 + rb + lr) * 512 + k0 + lc, &Bl[rb * 64]);
      }
    }
    __syncthreads();
#pragma unroll
    for (int kk = 0; kk < 2; ++kk) {
      const int koff = kk * 32 + (lane >> 4) * 8;
      const int ml = lane & 15;
      bf16x8 ah[2], bh[2], al[2], bl[2];
#pragma unroll
      for (int tm = 0; tm < 2; ++tm)
        ah[tm] = *(const bf16x8*)&Ah[(waveM * 32 + tm * 16 + ml) * 64 + koff];
#pragma unroll
      for (int tn = 0; tn < 2; ++tn)
        bh[tn] = *(const bf16x8*)&Bh[(waveN * 32 + tn * 16 + ml) * 64 + koff];
      if (comp) {
#pragma unroll
        for (int tm = 0; tm < 2; ++tm)
          al[tm] = *(const bf16x8*)&Al[(waveM * 32 + tm * 16 + ml) * 64 + koff];
#pragma unroll
        for (int tn = 0; tn < 2; ++tn)
          bl[tn] = *(const bf16x8*)&Bl[(waveN * 32 + tn * 16 + ml) * 64 + koff];
      }
#pragma unroll
      for (int tm = 0; tm < 2; ++tm)
#pragma unroll
        for (int tn = 0; tn < 2; ++tn) {
          acc[tm][tn] = __builtin_amdgcn_mfma_f32_16x16x32_bf16(ah[tm], bh[tn], acc[tm][tn], 0, 0, 0);
          if (comp) {
            acc[tm][tn] = __builtin_amdgcn_mfma_f32_16x16x32_bf16(ah[tm], bl[tn], acc[tm][tn], 0, 0, 0);
            acc[tm][tn] = __builtin_amdgcn_mfma_f32_16x16x32_bf16(al[tm], bh[tn], acc[tm][tn], 0, 0, 0);
          }
        }
    }
  }

  const int quad = lane >> 4, cl = lane & 15;
#pragma unroll
  for (int tm = 0; tm < 2; ++tm) {
#pragma unroll
    for (int r = 0; r < 4; ++r) {
      const int row = m0 + waveM * 32 + tm * 16 + quad * 4 + r;
#pragma unroll
      for (int tn = 0; tn < 2; ++tn) {
        const int col = n0 + waveN * 32 + tn * 16 + cl;
        float v = acc[tm][tn][r];
        if (o.bias) v += o.bias[col];
        if (o.add) v += o.add[(size_t)row * 512 + col];
        if (o.act) v = tanh_fast(v);
        if (o.outf) o.outf[(size_t)row * 512 + col] = v;
        if (o.outh) {
          __bf16 h = (__bf16)v;
          o.outh[(size_t)row * 512 + col] = h;
          o.outl[(size_t)row * 512 + col] = (__bf16)(v - (float)h);
        }
      }
    }
  }
}

// ------------- fused rel chain: block = (b, i, j-half), 64-row tile in LDS ------
// rel1 = tanh(A[i]+C[j]) -> [@Wgc +p1+q1 tanh] -> [@Wgc +p2+q2 tanh] -> @Wes+b -> S
// 512 threads (8 waves); wave w owns cols [w*64, w*64+64) (2 frags of 32).
// A-frags from LDS (stride 520 bf16); B-frags register-direct from
// fragment-packed weights with 2-deep prefetch (4 loads in flight per wave).
constexpr int RS = 520;  // rel row stride (bf16), 1040 B, 16B aligned

__global__ __launch_bounds__(512, 4) void chain_kernel(
    const float* __restrict__ Abuf, const float* __restrict__ Cbuf,
    const __bf16* __restrict__ Wgcf, const __bf16* __restrict__ Wesf,
    const float* __restrict__ p1, const float* __restrict__ q1,
    const float* __restrict__ p2, const float* __restrict__ q2,
    const float* __restrict__ b_esa, float* __restrict__ S) {
  __shared__ __bf16 rel[64 * RS];
  const int t = threadIdx.x;
  const int lane = t & 63, wave = t >> 6;
  const int bm = blockIdx.x >> 1;       // b*128 + i
  const int jh = (blockIdx.x & 1) * 64; // j-half base
  const int b = bm >> 7;

  // ---- rel1 generation: 8 threads per row (64 rows) ----
  {
    const int j = t >> 3, seg = (t & 7) * 64;
    const float* ap = &Abuf[(size_t)bm * 512 + seg];
    const float* cp = &Cbuf[((size_t)(b * 128 + jh + j)) * 512 + seg];
#pragma unroll
    for (int c = 0; c < 64; c += 8) {
      float4 a0 = *(const float4*)(ap + c), a1 = *(const float4*)(ap + c + 4);
      float4 c0 = *(const float4*)(cp + c), c1 = *(const float4*)(cp + c + 4);
      float av[8] = {a0.x + c0.x, a0.y + c0.y, a0.z + c0.z, a0.w + c0.w,
                     a1.x + c1.x, a1.y + c1.y, a1.z + c1.z, a1.w + c1.w};
      bf16x8 o;
#pragma unroll
      for (int e = 0; e < 8; ++e) o[e] = (__bf16)tanh_fast(av[e]);
      *(bf16x8*)&rel[j * RS + seg + c] = o;
    }
  }
  __syncthreads();

  const int ml = lane & 31;
  const int kg = (lane >> 5) * 8;
  const int lg = lane >> 5;
  // fragment-pack base offsets for this wave's two column-frags (tn=0,1)
  const size_t f0 = ((size_t)(wave * 2 + 0) * 32 * 64 + lane) * 8;
  const size_t f1 = ((size_t)(wave * 2 + 1) * 32 * 64 + lane) * 8;

  for (int l = 0; l < 3; ++l) {
    const __bf16* Wf = (l == 2) ? Wesf : Wgcf;
    f32x16 acc[2][2];
#pragma unroll
    for (int a = 0; a < 2; ++a)
#pragma unroll
      for (int c = 0; c < 2; ++c) acc[a][c] = (f32x16)0.f;

    // 2-deep software pipeline over kt (each kt-step = 512 B of W per wave-frag)
    bf16x8 c0 = *(const bf16x8*)&Wf[f0];
    bf16x8 c1 = *(const bf16x8*)&Wf[f1];
    bf16x8 n0 = *(const bf16x8*)&Wf[f0 + 512];
    bf16x8 n1 = *(const bf16x8*)&Wf[f1 + 512];
#pragma unroll 4
    for (int kt = 0; kt < 32; ++kt) {
      const size_t fo = (size_t)((kt + 2) & 31) * 512;
      bf16x8 u0 = *(const bf16x8*)&Wf[f0 + fo];
      bf16x8 u1 = *(const bf16x8*)&Wf[f1 + fo];
      bf16x8 af0 = *(const bf16x8*)&rel[(ml) * RS + kt * 16 + kg];
      bf16x8 af1 = *(const bf16x8*)&rel[(32 + ml) * RS + kt * 16 + kg];
      acc[0][0] = __builtin_amdgcn_mfma_f32_32x32x16_bf16(af0, c0, acc[0][0], 0, 0, 0);
      acc[0][1] = __builtin_amdgcn_mfma_f32_32x32x16_bf16(af0, c1, acc[0][1], 0, 0, 0);
      acc[1][0] = __builtin_amdgcn_mfma_f32_32x32x16_bf16(af1, c0, acc[1][0], 0, 0, 0);
      acc[1][1] = __builtin_amdgcn_mfma_f32_32x32x16_bf16(af1, c1, acc[1][1], 0, 0, 0);
      c0 = n0; c1 = n1; n0 = u0; n1 = u1;
    }

    if (l < 2) {
      const float* P = l ? p2 : p1;
      const float* Q = l ? q2 : q1;
      __syncthreads();  // all A-reads of this layer done before overwrite
#pragma unroll
      for (int tn = 0; tn < 2; ++tn) {
        const int col = wave * 64 + tn * 32 + ml;
        const float pv = P[(size_t)bm * 512 + col];
#pragma unroll
        for (int tm = 0; tm < 2; ++tm) {
#pragma unroll
          for (int reg = 0; reg < 16; ++reg) {
            const int row = tm * 32 + (reg & 3) + 8 * (reg >> 2) + 4 * lg;  // j local
            float v = acc[tm][tn][reg] + pv +
                      Q[((size_t)(b * 128 + jh + row)) * 512 + col];
            rel[row * RS + col] = (__bf16)tanh_fast(v);
          }
        }
      }
      __syncthreads();
    } else {
#pragma unroll
      for (int tn = 0; tn < 2; ++tn) {
        const int col = wave * 64 + tn * 32 + ml;
        const float bv = b_esa[col];
#pragma unroll
        for (int tm = 0; tm < 2; ++tm) {
#pragma unroll
          for (int reg = 0; reg < 16; ++reg) {
            const int row = tm * 32 + (reg & 3) + 8 * (reg >> 2) + 4 * lg;  // j local
            S[((size_t)bm * 128 + jh + row) * 512 + col] = acc[tm][tn][reg] + bv;
          }
        }
      }
    }
  }
}

// ------------- softmax over axis i (no max pass: |s| bounded), then sum over j --
__global__ __launch_bounds__(256) void softmax_l_kernel(
    const float* __restrict__ S, float* __restrict__ Lb) {
  int idx = blockIdx.x * 256 + threadIdx.x;   // = (b*128 + j)*512 + d
  int d = idx & 511;
  int j = (idx >> 9) & 127;
  int b = idx >> 16;
  const float* p = S + ((size_t)b * 16384 + j) * 512 + d;  // i = 0
  float l = 0.f;
#pragma unroll 8
  for (int ii = 0; ii < 128; ++ii) l += __expf(p[(size_t)ii * 65536]);
  Lb[idx] = __frcp_rn(l);
}

__global__ __launch_bounds__(256) void softmax_out_kernel(
    const float* __restrict__ S, const float* __restrict__ Lb,
    float* __restrict__ outp) {
  int idx = blockIdx.x * 256 + threadIdx.x;   // = (b*128 + i)*512 + d
  int d = idx & 511;
  int i = (idx >> 9) & 127;
  int b = idx >> 16;
  const float* sp = S + ((size_t)(b * 128 + i)) * 65536 + d;  // j = 0
  const float* lp = Lb + (size_t)b * 65536 + d;
  float acc = 0.f;
#pragma unroll 8
  for (int jj = 0; jj < 128; ++jj) {
    float s = sp[(size_t)jj * 512];
    acc += __expf(s) * lp[(size_t)jj * 512] * s;
  }
  outp[idx] = acc;
}

// --------------------------------------------------------------------------------
extern "C" void kernel_launch(void* const* d_in, const int* in_sizes, int n_in,
                              void* d_out, int out_size, void* d_ws, size_t ws_size,
                              hipStream_t stream) {
  const float* x0    = (const float*)d_in[0];
  const float* W_rel = (const float*)d_in[1];
  const float* b_rel = (const float*)d_in[2];
  const float* W_go  = (const float*)d_in[3];
  const float* b_go  = (const float*)d_in[4];
  const float* W_gr  = (const float*)d_in[5];
  const float* b_gr  = (const float*)d_in[6];
  const float* W_esa = (const float*)d_in[7];
  const float* b_esa = (const float*)d_in[8];

  const float* Wrel_top = W_rel;
  const float* Wrel_bot = W_rel + 512 * 512;
  const float* Wgr_a = W_gr;
  const float* Wgr_b = W_gr + 512 * 512;
  const float* Wgr_c = W_gr + 2 * 512 * 512;

  char* ws = (char*)d_ws;
  size_t off = 0;
  auto alloc = [&](size_t bytes) -> void* {
    void* p = ws + off;
    off += (bytes + 255) & ~(size_t)255;
    return p;
  };
  const size_t NREL = 16777216ull;
  float*  S  = (float*)alloc(NREL * 4);        // 64 MB
  float* p0t  = (float*)alloc(131072 * 4);
  float* q0t  = (float*)alloc(131072 * 4);
  float* Abuf = (float*)alloc(131072 * 4);
  float* Cbuf = (float*)alloc(131072 * 4);
  float* p1   = (float*)alloc(131072 * 4);
  float* q1   = (float*)alloc(131072 * 4);
  float* p2   = (float*)alloc(131072 * 4);
  float* q2   = (float*)alloc(131072 * 4);
  float* dvec = (float*)alloc(512 * 4);
  float* Lb   = (float*)alloc(131072 * 4);
  __bf16* x0h = (__bf16*)alloc(131072 * 2);
  __bf16* x0l = (__bf16*)alloc(131072 * 2);
  __bf16* x1h = (__bf16*)alloc(131072 * 2);
  __bf16* x1l = (__bf16*)alloc(131072 * 2);
  __bf16* x2h = (__bf16*)alloc(131072 * 2);
  __bf16* x2l = (__bf16*)alloc(131072 * 2);
  __bf16* u0h = (__bf16*)alloc(131072 * 2);
  __bf16* u0l = (__bf16*)alloc(131072 * 2);
  __bf16* v0h = (__bf16*)alloc(131072 * 2);
  __bf16* v0l = (__bf16*)alloc(131072 * 2);
  __bf16* Wgo_h = (__bf16*)alloc(262144 * 2);
  __bf16* Wgo_l = (__bf16*)alloc(262144 * 2);
  __bf16* Wrt_h = (__bf16*)alloc(262144 * 2);
  __bf16* Wrt_l = (__bf16*)alloc(262144 * 2);
  __bf16* Wrb_h = (__bf16*)alloc(262144 * 2);
  __bf16* Wrb_l = (__bf16*)alloc(262144 * 2);
  __bf16* Wga_h = (__bf16*)alloc(262144 * 2);
  __bf16* Wga_l = (__bf16*)alloc(262144 * 2);
  __bf16* Wgb_h = (__bf16*)alloc(262144 * 2);
  __bf16* Wgb_l = (__bf16*)alloc(262144 * 2);
  __bf16* Wgc_h = (__bf16*)alloc(262144 * 2);
  __bf16* Wgc_l = (__bf16*)alloc(262144 * 2);
  __bf16* Wgcf  = (__bf16*)alloc(262144 * 2);  // fragment-packed
  __bf16* Wesf  = (__bf16*)alloc(262144 * 2);  // fragment-packed

  float* x3out  = (float*)d_out;             // output 0
  float* relout = (float*)d_out + 131072;    // output 1

  Prep pp;
  pp.w[0] = {W_go, Wgo_h, Wgo_l};
  pp.w[1] = {Wrel_top, Wrt_h, Wrt_l};
  pp.w[2] = {Wrel_bot, Wrb_h, Wrb_l};
  pp.w[3] = {Wgr_a, Wga_h, Wga_l};
  pp.w[4] = {Wgr_b, Wgb_h, Wgb_l};
  pp.w[5] = {Wgr_c, Wgc_h, Wgc_l};
  pp.x0 = x0; pp.x0h = x0h; pp.x0l = x0l;
  pp.b_rel = b_rel; pp.Wgrc = Wgr_c; pp.b_gr = b_gr; pp.dvec = dvec;
  pp.Wesa = W_esa; pp.Wgcf = Wgcf; pp.Wesf = Wesf;
  prep_kernel<<<dim3(256, 10), 256, 0, stream>>>(pp);

  MBatch m1 = {};
  m1.op[0] = {x0h, x0l, Wgo_h, Wgo_l, b_go, nullptr, nullptr, x1h, x1l, 1};
  m1.op[1] = {x0h, x0l, Wrt_h, Wrt_l, nullptr, nullptr, nullptr, u0h, u0l, 0};
  m1.op[2] = {x0h, x0l, Wrb_h, Wrb_l, nullptr, nullptr, nullptr, v0h, v0l, 0};
  m1.op[3] = {x0h, x0l, Wga_h, Wga_l, nullptr, nullptr, p0t, nullptr, nullptr, 0};
  m1.op[4] = {x0h, x0l, Wgb_h, Wgb_l, nullptr, nullptr, q0t, nullptr, nullptr, 0};
  mfma_small_kernel<<<dim3(32, 5), 256, 0, stream>>>(m1);

  MBatch m2 = {};
  m2.op[0] = {x1h, x1l, Wgo_h, Wgo_l, b_go, nullptr, nullptr, x2h, x2l, 1};
  m2.op[1] = {u0h, u0l, Wgc_h, Wgc_l, dvec, p0t, Abuf, nullptr, nullptr, 0};
  m2.op[2] = {v0h, v0l, Wgc_h, Wgc_l, nullptr, q0t, Cbuf, nullptr, nullptr, 0};
  m2.op[3] = {x1h, x1l, Wga_h, Wga_l, b_gr, nullptr, p1, nullptr, nullptr, 0};
  m2.op[4] = {x1h, x1l, Wgb_h, Wgb_l, nullptr, nullptr, q1, nullptr, nullptr, 0};
  mfma_small_kernel<<<dim3(32, 5), 256, 0, stream>>>(m2);

  MBatch m3 = {};
  m3.op[0] = {x2h, x2l, Wgo_h, Wgo_l, b_go, nullptr, x3out, nullptr, nullptr, 1};
  m3.op[1] = {x2h, x2l, Wga_h, Wga_l, b_gr, nullptr, p2, nullptr, nullptr, 0};
  m3.op[2] = {x2h, x2l, Wgb_h, Wgb_l, nullptr, nullptr, q2, nullptr, nullptr, 0};
  mfma_small_kernel<<<dim3(32, 3), 256, 0, stream>>>(m3);

  // fused rel chain (replaces rel1 + 3 big GEMMs)
  chain_kernel<<<512, 512, 0, stream>>>(Abuf, Cbuf, Wgcf, Wesf,
                                        p1, q1, p2, q2, b_esa, S);

  softmax_l_kernel<<<512, 256, 0, stream>>>(S, Lb);
  softmax_out_kernel<<<512, 256, 0, stream>>>(S, Lb, relout);
}